// Round 2
// baseline (198.422 us; speedup 1.0000x reference)
//
#include <hip/hip_runtime.h>
#include <math.h>

#define B_  2
#define T_  2048
#define D_  512
#define H_  8
#define HD_ 64
#define QKVS (3*D_)   // 1536

typedef __bf16 bf16x8 __attribute__((ext_vector_type(8)));
typedef float  f32x4  __attribute__((ext_vector_type(4)));

__device__ inline unsigned short f2bf(float f) {   // RN-even fp32->bf16
  unsigned int u = __float_as_uint(f);
  return (unsigned short)((u + 0x7FFFu + ((u >> 16) & 1u)) >> 16);
}
__device__ inline unsigned int pack2bf(float lo, float hi) {
  return (unsigned int)f2bf(lo) | ((unsigned int)f2bf(hi) << 16);
}

// LDS fp32 x8 -> bf16x8 fragment (compiler emits v_cvt_pk_bf16_f32, RNE)
__device__ inline bf16x8 cvt8(const float* __restrict__ s) {
  float4 a = *(const float4*)s;
  float4 b = *(const float4*)(s + 4);
  bf16x8 r;
  r[0] = (__bf16)a.x; r[1] = (__bf16)a.y; r[2] = (__bf16)a.z; r[3] = (__bf16)a.w;
  r[4] = (__bf16)b.x; r[5] = (__bf16)b.y; r[6] = (__bf16)b.z; r[7] = (__bf16)b.w;
  return r;
}

// ---------------------------------------------------------------------------
// GEMM1: qkv projection, fp32 inputs (x, w_qkv) staged to LDS as fp32 via
// global_load_lds, converted to bf16 on the LDS->fragment read. Kills the
// separate cast kernel. 128x64 tile, BK=64 (2 x 32-K subpanels / round),
// LDS = 48 KB -> 3 blocks/CU. bf16 output (token-major qkvb).
// ---------------------------------------------------------------------------
__global__ __launch_bounds__(256, 3)
void gemm_qkv_f32(const float* __restrict__ A,    // x fp32 (M,K)
                  const float* __restrict__ Bw,   // w_qkv fp32 (N,K)
                  const float* __restrict__ bias,
                  unsigned short* __restrict__ C, // bf16 (M,N)
                  int M, int N, int K) {
  __shared__ __align__(16) float Asf[2][128 * 32];   // 2 x 16 KB
  __shared__ __align__(16) float Bsf[2][64 * 32];    // 2 x 8 KB

  const int tid = threadIdx.x;
  const int w   = tid >> 6;
  const int l   = tid & 63;
  const int wr  = w >> 1;
  const int wc  = w & 1;
  const int q   = l >> 4;
  const int ml  = l & 15;
  const int srow = tid >> 3;        // 0..31 within a 4KB issue
  const int scol = (tid & 7) * 4;   // float col (16 B)

  // bijective XCD swizzle (768 % 8 == 0): cluster col-blocks of one row-panel
  // on one XCD so the fp32 A-panel re-reads stay L2-local.
  int flat = blockIdx.y * gridDim.x + blockIdx.x;
  const int nb = gridDim.x * gridDim.y;
  flat = (flat & 7) * (nb >> 3) + (flat >> 3);
  const int bx = flat % gridDim.x, by = flat / gridDim.x;
  const int rowbase = by * 128;
  const int colbase = bx * 64;

  f32x4 acc[4][2] = {};

  for (int k0 = 0; k0 < K; k0 += 64) {
    __syncthreads();
    #pragma unroll
    for (int s = 0; s < 2; ++s) {
      const int kp = k0 + s * 32;
      #pragma unroll
      for (int i = 0; i < 4; ++i) {            // A: 128x32 f32 = 4 issues
        const float* g = A + (size_t)(rowbase + i * 32 + srow) * K + kp + scol;
        __builtin_amdgcn_global_load_lds(
            (const __attribute__((address_space(1))) void*)g,
            (__attribute__((address_space(3))) void*)
                ((char*)&Asf[s][0] + i * 4096 + w * 1024), 16, 0, 0);
      }
      #pragma unroll
      for (int i = 0; i < 2; ++i) {            // B: 64x32 f32 = 2 issues
        const float* g = Bw + (size_t)(colbase + i * 32 + srow) * K + kp + scol;
        __builtin_amdgcn_global_load_lds(
            (const __attribute__((address_space(1))) void*)g,
            (__attribute__((address_space(3))) void*)
                ((char*)&Bsf[s][0] + i * 4096 + w * 1024), 16, 0, 0);
      }
    }
    __syncthreads();

    #pragma unroll
    for (int s = 0; s < 2; ++s) {
      bf16x8 af[4], bfr[2];
      #pragma unroll
      for (int mi = 0; mi < 4; ++mi)
        af[mi] = cvt8(&Asf[s][(wr * 64 + mi * 16 + ml) * 32 + q * 8]);
      #pragma unroll
      for (int ni = 0; ni < 2; ++ni)
        bfr[ni] = cvt8(&Bsf[s][(wc * 32 + ni * 16 + ml) * 32 + q * 8]);
      #pragma unroll
      for (int mi = 0; mi < 4; ++mi)
        #pragma unroll
        for (int ni = 0; ni < 2; ++ni)
          acc[mi][ni] = __builtin_amdgcn_mfma_f32_16x16x32_bf16(
              af[mi], bfr[ni], acc[mi][ni], 0, 0, 0);
    }
  }

  #pragma unroll
  for (int mi = 0; mi < 4; ++mi) {
    #pragma unroll
    for (int ni = 0; ni < 2; ++ni) {
      const int col = colbase + wc * 32 + ni * 16 + ml;
      const float bv = bias[col];
      #pragma unroll
      for (int r = 0; r < 4; ++r) {
        const int row = rowbase + wr * 64 + mi * 16 + q * 4 + r;
        C[(size_t)row * N + col] = f2bf(acc[mi][ni][r] + bv);
      }
    }
  }
}

// ---------------------------------------------------------------------------
// GEMM2: output projection. A = attention output (bf16, gload_lds direct),
// B = w_out fp32 staged to LDS fp32, convert-on-read. 128x64 tile, BK=128
// (4 subpanels / round), LDS = 32+32 = 64 KB (grid is 1 block/CU anyway).
// fp32 output.
// ---------------------------------------------------------------------------
__global__ __launch_bounds__(256, 2)
void gemm_out_mix(const unsigned short* __restrict__ A, // bf16 (M,K)
                  const float* __restrict__ Bw,         // w_out fp32 (N,K)
                  const float* __restrict__ bias,
                  float* __restrict__ C,                // fp32 (M,N)
                  int M, int N, int K) {
  __shared__ __align__(16) short Ash[4][128 * 32];   // 4 x 8 KB
  __shared__ __align__(16) float Bsf[4][64 * 32];    // 4 x 8 KB

  const int tid = threadIdx.x;
  const int w   = tid >> 6;
  const int l   = tid & 63;
  const int wr  = w >> 1;
  const int wc  = w & 1;
  const int q   = l >> 4;
  const int ml  = l & 15;
  const int arow = tid >> 2, ach = (tid & 3) * 8;   // A: halves
  const int srow = tid >> 3, scol = (tid & 7) * 4;  // B: floats

  int flat = blockIdx.y * gridDim.x + blockIdx.x;   // 256 % 8 == 0
  const int nb = gridDim.x * gridDim.y;
  flat = (flat & 7) * (nb >> 3) + (flat >> 3);
  const int bx = flat % gridDim.x, by = flat / gridDim.x;
  const int rowbase = by * 128;
  const int colbase = bx * 64;

  f32x4 acc[4][2] = {};

  for (int k0 = 0; k0 < K; k0 += 128) {
    __syncthreads();
    #pragma unroll
    for (int s = 0; s < 4; ++s) {
      const int kp = k0 + s * 32;
      #pragma unroll
      for (int i = 0; i < 2; ++i) {            // A: 128x32 bf16 = 2 issues
        const unsigned short* g =
            A + (size_t)(rowbase + i * 64 + arow) * K + kp + ach;
        __builtin_amdgcn_global_load_lds(
            (const __attribute__((address_space(1))) void*)g,
            (__attribute__((address_space(3))) void*)
                ((char*)&Ash[s][0] + i * 4096 + w * 1024), 16, 0, 0);
      }
      #pragma unroll
      for (int i = 0; i < 2; ++i) {            // B: 64x32 f32 = 2 issues
        const float* g = Bw + (size_t)(colbase + i * 32 + srow) * K + kp + scol;
        __builtin_amdgcn_global_load_lds(
            (const __attribute__((address_space(1))) void*)g,
            (__attribute__((address_space(3))) void*)
                ((char*)&Bsf[s][0] + i * 4096 + w * 1024), 16, 0, 0);
      }
    }
    __syncthreads();

    #pragma unroll
    for (int s = 0; s < 4; ++s) {
      bf16x8 af[4], bfr[2];
      #pragma unroll
      for (int mi = 0; mi < 4; ++mi)
        af[mi] = *(const bf16x8*)&Ash[s][(wr * 64 + mi * 16 + ml) * 32 + q * 8];
      #pragma unroll
      for (int ni = 0; ni < 2; ++ni)
        bfr[ni] = cvt8(&Bsf[s][(wc * 32 + ni * 16 + ml) * 32 + q * 8]);
      #pragma unroll
      for (int mi = 0; mi < 4; ++mi)
        #pragma unroll
        for (int ni = 0; ni < 2; ++ni)
          acc[mi][ni] = __builtin_amdgcn_mfma_f32_16x16x32_bf16(
              af[mi], bfr[ni], acc[mi][ni], 0, 0, 0);
    }
  }

  #pragma unroll
  for (int mi = 0; mi < 4; ++mi) {
    #pragma unroll
    for (int ni = 0; ni < 2; ++ni) {
      const int col = colbase + wc * 32 + ni * 16 + ml;
      const float bv = bias[col];
      #pragma unroll
      for (int r = 0; r < 4; ++r) {
        const int row = rowbase + wr * 64 + mi * 16 + q * 4 + r;
        C[(size_t)row * N + col] = acc[mi][ni][r] + bv;
      }
    }
  }
}

// ---------------------------------------------------------------------------
// Residue-class flash attention, 64-query stripes, SPLIT-K across wave halves
// (unchanged from the verified 107.5 us version).
// ---------------------------------------------------------------------------
__global__ __launch_bounds__(512)
void attn_flash4(const unsigned short* __restrict__ qkv,
                 const int* __restrict__ periods,
                 unsigned short* __restrict__ ao) {
  const int bh = blockIdx.x, slot = 62 - blockIdx.y;   // heavy-first
  int p = periods[bh]; if (p < 1) p = 1;
  const int g  = slot / p;
  const int r  = slot - g * p;
  const int L  = (T_ - 1 - r) / p + 1;   // tokens in this residue class
  const int q0 = g << 6;                 // stripe base (t-space)
  if (q0 >= L) return;
  const int b = bh >> 3, h = bh & 7;
  const int Lrem = L - q0;               // >= 1
  const int Nkb  = min(L, q0 + 64);      // keys needed by the whole stripe

  const int tid  = threadIdx.x;
  const int w    = tid >> 6;             // wave 0..7
  const int wq   = w & 3;                // query sub-tile id (shared by halves)
  const int half = tid >> 8;             // key-split half: 0 or 1
  const int tl   = tid & 255;            // thread id within the half
  const int lane = tid & 63;
  const int Q = lane >> 4, c = lane & 15;

  __shared__ __align__(16) unsigned short Qs[64 * 72];       // 9216 B
  __shared__ __align__(16) unsigned short Ks[2][64 * 72];    // 2 x 9216 B
  __shared__ __align__(16) unsigned short Vt[2][64 * 72];    // 2 x 9216 B, [d][key]

  const size_t rowb = (size_t)b * T_ * QKVS + (size_t)h * HD_;

  // ---- stage Q stripe (64 rows x 64 halfs): 16 B per thread, 512 threads ----
  {
    const int u = tid >> 3, ch4 = (tid & 7) * 8;
    const int t = q0 + min(u, Lrem - 1);            // clamp (dup row, masked)
    const unsigned short* gq = qkv + rowb + (size_t)(r + t * p) * QKVS + ch4;
    *(int4*)&Qs[u * 72 + ch4] = *(const int4*)gq;
  }
  __syncthreads();
  bf16x8 qf[2];                          // B-frag: B[k=d=Q*8+j(+32)][n=q=c]
  qf[0] = *(const bf16x8*)&Qs[(wq * 16 + c) * 72 + Q * 8];
  qf[1] = *(const bf16x8*)&Qs[(wq * 16 + c) * 72 + Q * 8 + 32];

  const int qb      = wq * 16;           // wave's query offset in stripe
  const int nqw     = min(16, Lrem - qb);// <=0 -> inactive wave (barriers only)
  const int qglob   = q0 + qb + c;       // this lane's query t-index
  const int mylastk = q0 + qb + 15;      // last key this wave can need

  float m_run = -3.0e38f, l_run = 0.f;
  f32x4 o[4] = {};
  const size_t kb = rowb + D_;
  const size_t vb = rowb + 2 * D_;

  // staging assignments (per 256-thread half, 64-key tiles)
  const int krow = tl >> 2, koff = (tl & 3) * 16;      // K: 2x16B/thread
  const int vkey = tl & 63, vd0 = ((tl >> 6) & 3) * 8; // V: 2x16B/thread

  // key-range split: half 0 -> rounds [0, RA), half 1 -> rounds [RA, R)
  const int R     = (Nkb + 63) >> 6;     // total 64-key rounds
  const int RA    = (R + 1) >> 1;        // rounds for half 0 (>= half 1's)
  const int myR   = half ? (R - RA) : RA;
  const int kbase = half ? (RA << 6) : 0;

  // ---- prefetch this half's round 0 ----
  int4 kp0, kp1, vp0, vp1;
  if (myR > 0) {
    const int tk = min(kbase + krow, Nkb - 1);
    const int tv = min(kbase + vkey, Nkb - 1);
    const unsigned short* gk = qkv + kb + (size_t)(r + tk * p) * QKVS + koff;
    const unsigned short* gv = qkv + vb + (size_t)(r + tv * p) * QKVS;
    kp0 = ((const int4*)gk)[0];
    kp1 = ((const int4*)gk)[1];
    vp0 = *(const int4*)(gv + vd0);
    vp1 = *(const int4*)(gv + vd0 + 32);
  }

  // uniform trip count (RA >= myR for both halves) -> barriers never diverge
  for (int rr = 0; rr < RA; ++rr) {
    const int k0 = kbase + (rr << 6);    // absolute key base of this round
    __syncthreads();                     // prev round's frag reads complete
    if (rr < myR) {
      // ---- commit prefetched K (row-major) + V (transposed) ----
      *(int4*)&Ks[half][krow * 72 + koff + 0] = kp0;
      *(int4*)&Ks[half][krow * 72 + koff + 8] = kp1;
      unsigned short vh0[8], vh1[8];
      *(int4*)vh0 = vp0;
      *(int4*)vh1 = vp1;
      #pragma unroll
      for (int j = 0; j < 8; ++j) {
        Vt[half][(vd0 + j) * 72 + vkey]      = vh0[j];
        Vt[half][(vd0 + 32 + j) * 72 + vkey] = vh1[j];
      }
    }
    __syncthreads();                     // LDS valid

    // ---- issue next round's global loads (hide behind compute) ----
    if (rr + 1 < myR) {
      const int tk = min(k0 + 64 + krow, Nkb - 1);
      const int tv = min(k0 + 64 + vkey, Nkb - 1);
      const unsigned short* gk = qkv + kb + (size_t)(r + tk * p) * QKVS + koff;
      const unsigned short* gv = qkv + vb + (size_t)(r + tv * p) * QKVS;
      kp0 = ((const int4*)gk)[0];
      kp1 = ((const int4*)gk)[1];
      vp0 = *(const int4*)(gv + vd0);
      vp1 = *(const int4*)(gv + vd0 + 32);
    }

    if (rr < myR && nqw > 0 && k0 <= mylastk) {
      // ---- S^T tiles (4 x 16 keys), per-tile skip ----
      float pvv[16];
      float tmax = -3.0e38f;
      #pragma unroll
      for (int mt = 0; mt < 4; ++mt) {
        if (k0 + mt * 16 <= mylastk) {
          bf16x8 a0 = *(const bf16x8*)&Ks[half][(mt * 16 + c) * 72 + Q * 8];
          bf16x8 a1 = *(const bf16x8*)&Ks[half][(mt * 16 + c) * 72 + Q * 8 + 32];
          f32x4 s = {};
          s = __builtin_amdgcn_mfma_f32_16x16x32_bf16(a0, qf[0], s, 0, 0, 0);
          s = __builtin_amdgcn_mfma_f32_16x16x32_bf16(a1, qf[1], s, 0, 0, 0);
          #pragma unroll
          for (int rg = 0; rg < 4; ++rg) {
            const int kk = k0 + mt * 16 + Q * 4 + rg;   // key t-index
            float v = s[rg] * 0.125f;                   // 1/sqrt(HD)
            v = (kk <= qglob) ? v : -3.0e38f;
            pvv[mt * 4 + rg] = v;
            tmax = fmaxf(tmax, v);
          }
        } else {
          #pragma unroll
          for (int rg = 0; rg < 4; ++rg) pvv[mt * 4 + rg] = -3.0e38f;
        }
      }

      // ---- online softmax per column (q = c) ----
      tmax = fmaxf(tmax, __shfl_xor(tmax, 16));
      tmax = fmaxf(tmax, __shfl_xor(tmax, 32));
      const float m_new = fmaxf(m_run, tmax);
      const float alpha = __expf(m_run - m_new);
      float tsum = 0.f;
      #pragma unroll
      for (int i = 0; i < 16; ++i) {
        pvv[i] = __expf(pvv[i] - m_new);
        tsum += pvv[i];
      }
      tsum += __shfl_xor(tsum, 16);
      tsum += __shfl_xor(tsum, 32);
      l_run = l_run * alpha + tsum;
      m_run = m_new;

      // ---- P^T -> B-operand frags per 32-key chunk ----
      bf16x8 pb[2];
      const int sq2 = (Q & 1) << 1;
      #pragma unroll
      for (int kc = 0; kc < 2; ++kc) {
        unsigned int pk0[2], pk1[2];
        pk0[0] = pack2bf(pvv[kc * 8 + 0], pvv[kc * 8 + 1]);
        pk0[1] = pack2bf(pvv[kc * 8 + 2], pvv[kc * 8 + 3]);
        pk1[0] = pack2bf(pvv[kc * 8 + 4], pvv[kc * 8 + 5]);
        pk1[1] = pack2bf(pvv[kc * 8 + 6], pvv[kc * 8 + 7]);
        int dw[4];
        #pragma unroll
        for (int d = 0; d < 4; ++d) {
          const int src = ((sq2 + (d >> 1)) << 4) + c;
          const int v0 = __shfl((int)pk0[d & 1], src);
          const int v1 = __shfl((int)pk1[d & 1], src);
          dw[d] = (Q >= 2) ? v1 : v0;
        }
        int4 bi = make_int4(dw[0], dw[1], dw[2], dw[3]);
        pb[kc] = *(bf16x8*)&bi;
      }

      // ---- O^T += V^T . P^T  (2 key-chunks x 4 d-chunks) ----
      #pragma unroll
      for (int ch = 0; ch < 4; ++ch)
        #pragma unroll
        for (int t2 = 0; t2 < 4; ++t2) o[ch][t2] *= alpha;
      #pragma unroll
      for (int kc = 0; kc < 2; ++kc) {
        if (k0 + kc * 32 <= mylastk) {
          #pragma unroll
          for (int ch = 0; ch < 4; ++ch) {
            bf16x8 af =
                *(const bf16x8*)&Vt[half][(ch * 16 + c) * 72 + kc * 32 + Q * 8];
            o[ch] = __builtin_amdgcn_mfma_f32_16x16x32_bf16(af, pb[kc], o[ch],
                                                            0, 0, 0);
          }
        }
      }
    }
  }

  // ---- merge the two key-half partials (LDS, intra-block) ----
  __syncthreads();                       // all K/V LDS reads done; reuse it
  float* obuf = (float*)&Ks[0][0];       // [4 waves][64 lanes][stride 17] f32
  float* mlb  = (float*)&Vt[0][0];       // [4 waves][32] f32 (m then l)
  if (half && nqw > 0) {
    float* ob = &obuf[(wq * 64 + lane) * 17];   // stride 17: conflict-free
    #pragma unroll
    for (int ch = 0; ch < 4; ++ch)
      #pragma unroll
      for (int t2 = 0; t2 < 4; ++t2) ob[ch * 4 + t2] = o[ch][t2];
    if (Q == 0) { mlb[wq * 32 + c] = m_run; mlb[wq * 32 + 16 + c] = l_run; }
  }
  __syncthreads();

  // ---- epilogue: O[q][d] = (wA*oA + wB*oB)[d][q] / L  (waves 0-3) ----
  if (!half && nqw > 0 && c < nqw) {
    const float mB = mlb[wq * 32 + c];
    const float lB = mlb[wq * 32 + 16 + c];
    const float M  = fmaxf(m_run, mB);
    const float wA = __expf(m_run - M);   // exp(-3e38 - M) == 0 handles empty
    const float wB = __expf(mB - M);      // halves / fully-masked partials
    const float invl = 1.f / (wA * l_run + wB * lB);
    const float* ob = &obuf[(wq * 64 + lane) * 17];
    const int tok = r + (q0 + qb + c) * p;
    unsigned int* dst =
        (unsigned int*)(ao + (size_t)(b * T_ + tok) * D_ + h * HD_);
    #pragma unroll
    for (int ch = 0; ch < 4; ++ch)
      #pragma unroll
      for (int rp = 0; rp < 2; ++rp) {
        const int dhalf = ch * 16 + Q * 4 + rp * 2;   // even
        const float v0 =
            (wA * o[ch][rp * 2]     + wB * ob[ch * 4 + rp * 2])     * invl;
        const float v1 =
            (wA * o[ch][rp * 2 + 1] + wB * ob[ch * 4 + rp * 2 + 1]) * invl;
        dst[dhalf >> 1] = pack2bf(v0, v1);
      }
  }
}

// ---------------------------------------------------------------------------
extern "C" void kernel_launch(void* const* d_in, const int* in_sizes, int n_in,
                              void* d_out, int out_size, void* d_ws, size_t ws_size,
                              hipStream_t stream) {
  const float* x      = (const float*)d_in[0];   // (B,T,D)
  const int*   period = (const int*)  d_in[1];   // (B,H)
  const float* w_qkv  = (const float*)d_in[2];   // (3D, D)
  const float* b_qkv  = (const float*)d_in[3];   // (3D,)
  const float* w_out  = (const float*)d_in[4];   // (D, D)
  const float* b_out  = (const float*)d_in[5];   // (D,)
  float* out = (float*)d_out;                    // (B,T,D)

  const int M = B_ * T_;                         // 4096

  // ws layout: qkvb [0,12 MB) bf16, aob [12,16 MB) bf16
  char* ws = (char*)d_ws;
  unsigned short* qkvb = (unsigned short*)(ws);
  unsigned short* aob  = (unsigned short*)(ws + (size_t)M * QKVS * 2);

  // 1) QKV projection straight from fp32 inputs -> bf16 token-major qkvb
  gemm_qkv_f32<<<dim3(QKVS / 64, M / 128), dim3(256), 0, stream>>>(
      x, w_qkv, b_qkv, qkvb, M, QKVS, D_);

  // 2) residue-class flash attention, split-K halves (512 threads) -> aob
  attn_flash4<<<dim3(16, 63), dim3(512), 0, stream>>>(qkvb, period, aob);

  // 3) output projection (A bf16, B fp32) -> fp32 out
  gemm_out_mix<<<dim3(D_ / 64, M / 128), dim3(256), 0, stream>>>(
      aob, w_out, b_out, out, M, D_, D_);
}

// Round 3
// 111.668 us; speedup vs baseline: 1.7769x; 1.7769x over previous
//
#include <hip/hip_runtime.h>
#include <math.h>

#define B_  2
#define T_  2048
#define D_  512
#define H_  8
#define HD_ 64
#define QKVS (3*D_)   // 1536

typedef __bf16 bf16x8 __attribute__((ext_vector_type(8)));
typedef float  f32x4  __attribute__((ext_vector_type(4)));

__device__ inline unsigned short f2bf(float f) {   // RN-even fp32->bf16
  unsigned int u = __float_as_uint(f);
  return (unsigned short)((u + 0x7FFFu + ((u >> 16) & 1u)) >> 16);
}
__device__ inline unsigned int pack2bf(float lo, float hi) {
  return (unsigned int)f2bf(lo) | ((unsigned int)f2bf(hi) << 16);
}

// Swizzled LDS fp32 x8 -> bf16x8 fragment. Tile is [rows][32 floats] with
// byte-swizzle  byte ^= (row&7)<<4  (16-B slot XOR within each 8-row stripe)
// -> the 16 lanes sharing q but differing in row hit 8 distinct slots
// (2-way bank alias = free) instead of the same 4 banks (16-way).
__device__ inline bf16x8 cvt8sw(const float* __restrict__ base, int row, int q) {
  const char* pb = (const char*)base;
  const int by = row * 128 + q * 32;
  const int sw = (row & 7) << 4;
  float4 a = *(const float4*)(pb + (by ^ sw));
  float4 b = *(const float4*)(pb + ((by + 16) ^ sw));
  bf16x8 r;
  r[0] = (__bf16)a.x; r[1] = (__bf16)a.y; r[2] = (__bf16)a.z; r[3] = (__bf16)a.w;
  r[4] = (__bf16)b.x; r[5] = (__bf16)b.y; r[6] = (__bf16)b.z; r[7] = (__bf16)b.w;
  return r;
}

// ---------------------------------------------------------------------------
// GEMM1: qkv projection, fp32 inputs staged to LDS fp32 via global_load_lds
// (LDS dest linear; the swizzle is applied by permuting the GLOBAL source
// column-chunk: slot = (tid&7) ^ (srow&7) -- same involution as the read).
// 128x64 tile, BK=64, LDS = 48 KB -> 3 blocks/CU. bf16 output.
// ---------------------------------------------------------------------------
__global__ __launch_bounds__(256, 3)
void gemm_qkv_f32(const float* __restrict__ A,    // x fp32 (M,K)
                  const float* __restrict__ Bw,   // w_qkv fp32 (N,K)
                  const float* __restrict__ bias,
                  unsigned short* __restrict__ C, // bf16 (M,N)
                  int M, int N, int K) {
  __shared__ __align__(16) float Asf[2][128 * 32];   // 2 x 16 KB
  __shared__ __align__(16) float Bsf[2][64 * 32];    // 2 x 8 KB

  const int tid = threadIdx.x;
  const int w   = tid >> 6;
  const int l   = tid & 63;
  const int wr  = w >> 1;
  const int wc  = w & 1;
  const int q   = l >> 4;
  const int ml  = l & 15;
  const int srow = tid >> 3;                        // row within a 32-row issue
  const int scol = ((tid & 7) ^ (srow & 7)) * 4;    // swizzled float col

  // bijective XCD swizzle (768 % 8 == 0)
  int flat = blockIdx.y * gridDim.x + blockIdx.x;
  const int nb = gridDim.x * gridDim.y;
  flat = (flat & 7) * (nb >> 3) + (flat >> 3);
  const int bx = flat % gridDim.x, by = flat / gridDim.x;
  const int rowbase = by * 128;
  const int colbase = bx * 64;

  f32x4 acc[4][2] = {};

  for (int k0 = 0; k0 < K; k0 += 64) {
    __syncthreads();
    #pragma unroll
    for (int s = 0; s < 2; ++s) {
      const int kp = k0 + s * 32;
      #pragma unroll
      for (int i = 0; i < 4; ++i) {            // A: 128x32 f32 = 4 issues
        const float* g = A + (size_t)(rowbase + i * 32 + srow) * K + kp + scol;
        __builtin_amdgcn_global_load_lds(
            (const __attribute__((address_space(1))) void*)g,
            (__attribute__((address_space(3))) void*)
                ((char*)&Asf[s][0] + i * 4096 + w * 1024), 16, 0, 0);
      }
      #pragma unroll
      for (int i = 0; i < 2; ++i) {            // B: 64x32 f32 = 2 issues
        const float* g = Bw + (size_t)(colbase + i * 32 + srow) * K + kp + scol;
        __builtin_amdgcn_global_load_lds(
            (const __attribute__((address_space(1))) void*)g,
            (__attribute__((address_space(3))) void*)
                ((char*)&Bsf[s][0] + i * 4096 + w * 1024), 16, 0, 0);
      }
    }
    __syncthreads();

    #pragma unroll
    for (int s = 0; s < 2; ++s) {
      bf16x8 af[4], bfr[2];
      #pragma unroll
      for (int mi = 0; mi < 4; ++mi)
        af[mi] = cvt8sw(&Asf[s][0], wr * 64 + mi * 16 + ml, q);
      #pragma unroll
      for (int ni = 0; ni < 2; ++ni)
        bfr[ni] = cvt8sw(&Bsf[s][0], wc * 32 + ni * 16 + ml, q);
      #pragma unroll
      for (int mi = 0; mi < 4; ++mi)
        #pragma unroll
        for (int ni = 0; ni < 2; ++ni)
          acc[mi][ni] = __builtin_amdgcn_mfma_f32_16x16x32_bf16(
              af[mi], bfr[ni], acc[mi][ni], 0, 0, 0);
    }
  }

  #pragma unroll
  for (int mi = 0; mi < 4; ++mi) {
    #pragma unroll
    for (int ni = 0; ni < 2; ++ni) {
      const int col = colbase + wc * 32 + ni * 16 + ml;
      const float bv = bias[col];
      #pragma unroll
      for (int r = 0; r < 4; ++r) {
        const int row = rowbase + wr * 64 + mi * 16 + q * 4 + r;
        C[(size_t)row * N + col] = f2bf(acc[mi][ni][r] + bv);
      }
    }
  }
}

// ---------------------------------------------------------------------------
// GEMM2: output projection. A = attention output (bf16, m97-layout, 64-B row
// stride -- proven regime), B = w_out fp32 staged swizzled like GEMM1.
// 128x64 tile, BK=128, LDS = 64 KB. fp32 output.
// ---------------------------------------------------------------------------
__global__ __launch_bounds__(256, 2)
void gemm_out_mix(const unsigned short* __restrict__ A, // bf16 (M,K)
                  const float* __restrict__ Bw,         // w_out fp32 (N,K)
                  const float* __restrict__ bias,
                  float* __restrict__ C,                // fp32 (M,N)
                  int M, int N, int K) {
  __shared__ __align__(16) short Ash[4][128 * 32];   // 4 x 8 KB
  __shared__ __align__(16) float Bsf[4][64 * 32];    // 4 x 8 KB

  const int tid = threadIdx.x;
  const int w   = tid >> 6;
  const int l   = tid & 63;
  const int wr  = w >> 1;
  const int wc  = w & 1;
  const int q   = l >> 4;
  const int ml  = l & 15;
  const int arow = tid >> 2, ach = (tid & 3) * 8;   // A: halves (linear)
  const int srow = tid >> 3;
  const int scol = ((tid & 7) ^ (srow & 7)) * 4;    // B: swizzled float col

  int flat = blockIdx.y * gridDim.x + blockIdx.x;   // 256 % 8 == 0
  const int nb = gridDim.x * gridDim.y;
  flat = (flat & 7) * (nb >> 3) + (flat >> 3);
  const int bx = flat % gridDim.x, by = flat / gridDim.x;
  const int rowbase = by * 128;
  const int colbase = bx * 64;

  f32x4 acc[4][2] = {};

  for (int k0 = 0; k0 < K; k0 += 128) {
    __syncthreads();
    #pragma unroll
    for (int s = 0; s < 4; ++s) {
      const int kp = k0 + s * 32;
      #pragma unroll
      for (int i = 0; i < 2; ++i) {            // A: 128x32 bf16 = 2 issues
        const unsigned short* g =
            A + (size_t)(rowbase + i * 64 + arow) * K + kp + ach;
        __builtin_amdgcn_global_load_lds(
            (const __attribute__((address_space(1))) void*)g,
            (__attribute__((address_space(3))) void*)
                ((char*)&Ash[s][0] + i * 4096 + w * 1024), 16, 0, 0);
      }
      #pragma unroll
      for (int i = 0; i < 2; ++i) {            // B: 64x32 f32 = 2 issues
        const float* g = Bw + (size_t)(colbase + i * 32 + srow) * K + kp + scol;
        __builtin_amdgcn_global_load_lds(
            (const __attribute__((address_space(1))) void*)g,
            (__attribute__((address_space(3))) void*)
                ((char*)&Bsf[s][0] + i * 4096 + w * 1024), 16, 0, 0);
      }
    }
    __syncthreads();

    #pragma unroll
    for (int s = 0; s < 4; ++s) {
      bf16x8 af[4], bfr[2];
      #pragma unroll
      for (int mi = 0; mi < 4; ++mi)
        af[mi] = *(const bf16x8*)&Ash[s][(wr * 64 + mi * 16 + ml) * 32 + q * 8];
      #pragma unroll
      for (int ni = 0; ni < 2; ++ni)
        bfr[ni] = cvt8sw(&Bsf[s][0], wc * 32 + ni * 16 + ml, q);
      #pragma unroll
      for (int mi = 0; mi < 4; ++mi)
        #pragma unroll
        for (int ni = 0; ni < 2; ++ni)
          acc[mi][ni] = __builtin_amdgcn_mfma_f32_16x16x32_bf16(
              af[mi], bfr[ni], acc[mi][ni], 0, 0, 0);
    }
  }

  #pragma unroll
  for (int mi = 0; mi < 4; ++mi) {
    #pragma unroll
    for (int ni = 0; ni < 2; ++ni) {
      const int col = colbase + wc * 32 + ni * 16 + ml;
      const float bv = bias[col];
      #pragma unroll
      for (int r = 0; r < 4; ++r) {
        const int row = rowbase + wr * 64 + mi * 16 + q * 4 + r;
        C[(size_t)row * N + col] = acc[mi][ni][r] + bv;
      }
    }
  }
}

// ---------------------------------------------------------------------------
// Residue-class flash attention, 64-query stripes, SPLIT-K across wave halves
// (unchanged from the verified 107.5 us version).
// ---------------------------------------------------------------------------
__global__ __launch_bounds__(512)
void attn_flash4(const unsigned short* __restrict__ qkv,
                 const int* __restrict__ periods,
                 unsigned short* __restrict__ ao) {
  const int bh = blockIdx.x, slot = 62 - blockIdx.y;   // heavy-first
  int p = periods[bh]; if (p < 1) p = 1;
  const int g  = slot / p;
  const int r  = slot - g * p;
  const int L  = (T_ - 1 - r) / p + 1;   // tokens in this residue class
  const int q0 = g << 6;                 // stripe base (t-space)
  if (q0 >= L) return;
  const int b = bh >> 3, h = bh & 7;
  const int Lrem = L - q0;               // >= 1
  const int Nkb  = min(L, q0 + 64);      // keys needed by the whole stripe

  const int tid  = threadIdx.x;
  const int w    = tid >> 6;             // wave 0..7
  const int wq   = w & 3;                // query sub-tile id (shared by halves)
  const int half = tid >> 8;             // key-split half: 0 or 1
  const int tl   = tid & 255;            // thread id within the half
  const int lane = tid & 63;
  const int Q = lane >> 4, c = lane & 15;

  __shared__ __align__(16) unsigned short Qs[64 * 72];       // 9216 B
  __shared__ __align__(16) unsigned short Ks[2][64 * 72];    // 2 x 9216 B
  __shared__ __align__(16) unsigned short Vt[2][64 * 72];    // 2 x 9216 B, [d][key]

  const size_t rowb = (size_t)b * T_ * QKVS + (size_t)h * HD_;

  // ---- stage Q stripe (64 rows x 64 halfs): 16 B per thread, 512 threads ----
  {
    const int u = tid >> 3, ch4 = (tid & 7) * 8;
    const int t = q0 + min(u, Lrem - 1);            // clamp (dup row, masked)
    const unsigned short* gq = qkv + rowb + (size_t)(r + t * p) * QKVS + ch4;
    *(int4*)&Qs[u * 72 + ch4] = *(const int4*)gq;
  }
  __syncthreads();
  bf16x8 qf[2];                          // B-frag: B[k=d=Q*8+j(+32)][n=q=c]
  qf[0] = *(const bf16x8*)&Qs[(wq * 16 + c) * 72 + Q * 8];
  qf[1] = *(const bf16x8*)&Qs[(wq * 16 + c) * 72 + Q * 8 + 32];

  const int qb      = wq * 16;           // wave's query offset in stripe
  const int nqw     = min(16, Lrem - qb);// <=0 -> inactive wave (barriers only)
  const int qglob   = q0 + qb + c;       // this lane's query t-index
  const int mylastk = q0 + qb + 15;      // last key this wave can need

  float m_run = -3.0e38f, l_run = 0.f;
  f32x4 o[4] = {};
  const size_t kb = rowb + D_;
  const size_t vb = rowb + 2 * D_;

  // staging assignments (per 256-thread half, 64-key tiles)
  const int krow = tl >> 2, koff = (tl & 3) * 16;      // K: 2x16B/thread
  const int vkey = tl & 63, vd0 = ((tl >> 6) & 3) * 8; // V: 2x16B/thread

  // key-range split: half 0 -> rounds [0, RA), half 1 -> rounds [RA, R)
  const int R     = (Nkb + 63) >> 6;     // total 64-key rounds
  const int RA    = (R + 1) >> 1;        // rounds for half 0 (>= half 1's)
  const int myR   = half ? (R - RA) : RA;
  const int kbase = half ? (RA << 6) : 0;

  // ---- prefetch this half's round 0 ----
  int4 kp0, kp1, vp0, vp1;
  if (myR > 0) {
    const int tk = min(kbase + krow, Nkb - 1);
    const int tv = min(kbase + vkey, Nkb - 1);
    const unsigned short* gk = qkv + kb + (size_t)(r + tk * p) * QKVS + koff;
    const unsigned short* gv = qkv + vb + (size_t)(r + tv * p) * QKVS;
    kp0 = ((const int4*)gk)[0];
    kp1 = ((const int4*)gk)[1];
    vp0 = *(const int4*)(gv + vd0);
    vp1 = *(const int4*)(gv + vd0 + 32);
  }

  // uniform trip count (RA >= myR for both halves) -> barriers never diverge
  for (int rr = 0; rr < RA; ++rr) {
    const int k0 = kbase + (rr << 6);    // absolute key base of this round
    __syncthreads();                     // prev round's frag reads complete
    if (rr < myR) {
      // ---- commit prefetched K (row-major) + V (transposed) ----
      *(int4*)&Ks[half][krow * 72 + koff + 0] = kp0;
      *(int4*)&Ks[half][krow * 72 + koff + 8] = kp1;
      unsigned short vh0[8], vh1[8];
      *(int4*)vh0 = vp0;
      *(int4*)vh1 = vp1;
      #pragma unroll
      for (int j = 0; j < 8; ++j) {
        Vt[half][(vd0 + j) * 72 + vkey]      = vh0[j];
        Vt[half][(vd0 + 32 + j) * 72 + vkey] = vh1[j];
      }
    }
    __syncthreads();                     // LDS valid

    // ---- issue next round's global loads (hide behind compute) ----
    if (rr + 1 < myR) {
      const int tk = min(k0 + 64 + krow, Nkb - 1);
      const int tv = min(k0 + 64 + vkey, Nkb - 1);
      const unsigned short* gk = qkv + kb + (size_t)(r + tk * p) * QKVS + koff;
      const unsigned short* gv = qkv + vb + (size_t)(r + tv * p) * QKVS;
      kp0 = ((const int4*)gk)[0];
      kp1 = ((const int4*)gk)[1];
      vp0 = *(const int4*)(gv + vd0);
      vp1 = *(const int4*)(gv + vd0 + 32);
    }

    if (rr < myR && nqw > 0 && k0 <= mylastk) {
      // ---- S^T tiles (4 x 16 keys), per-tile skip ----
      float pvv[16];
      float tmax = -3.0e38f;
      #pragma unroll
      for (int mt = 0; mt < 4; ++mt) {
        if (k0 + mt * 16 <= mylastk) {
          bf16x8 a0 = *(const bf16x8*)&Ks[half][(mt * 16 + c) * 72 + Q * 8];
          bf16x8 a1 = *(const bf16x8*)&Ks[half][(mt * 16 + c) * 72 + Q * 8 + 32];
          f32x4 s = {};
          s = __builtin_amdgcn_mfma_f32_16x16x32_bf16(a0, qf[0], s, 0, 0, 0);
          s = __builtin_amdgcn_mfma_f32_16x16x32_bf16(a1, qf[1], s, 0, 0, 0);
          #pragma unroll
          for (int rg = 0; rg < 4; ++rg) {
            const int kk = k0 + mt * 16 + Q * 4 + rg;   // key t-index
            float v = s[rg] * 0.125f;                   // 1/sqrt(HD)
            v = (kk <= qglob) ? v : -3.0e38f;
            pvv[mt * 4 + rg] = v;
            tmax = fmaxf(tmax, v);
          }
        } else {
          #pragma unroll
          for (int rg = 0; rg < 4; ++rg) pvv[mt * 4 + rg] = -3.0e38f;
        }
      }

      // ---- online softmax per column (q = c) ----
      tmax = fmaxf(tmax, __shfl_xor(tmax, 16));
      tmax = fmaxf(tmax, __shfl_xor(tmax, 32));
      const float m_new = fmaxf(m_run, tmax);
      const float alpha = __expf(m_run - m_new);
      float tsum = 0.f;
      #pragma unroll
      for (int i = 0; i < 16; ++i) {
        pvv[i] = __expf(pvv[i] - m_new);
        tsum += pvv[i];
      }
      tsum += __shfl_xor(tsum, 16);
      tsum += __shfl_xor(tsum, 32);
      l_run = l_run * alpha + tsum;
      m_run = m_new;

      // ---- P^T -> B-operand frags per 32-key chunk ----
      bf16x8 pb[2];
      const int sq2 = (Q & 1) << 1;
      #pragma unroll
      for (int kc = 0; kc < 2; ++kc) {
        unsigned int pk0[2], pk1[2];
        pk0[0] = pack2bf(pvv[kc * 8 + 0], pvv[kc * 8 + 1]);
        pk0[1] = pack2bf(pvv[kc * 8 + 2], pvv[kc * 8 + 3]);
        pk1[0] = pack2bf(pvv[kc * 8 + 4], pvv[kc * 8 + 5]);
        pk1[1] = pack2bf(pvv[kc * 8 + 6], pvv[kc * 8 + 7]);
        int dw[4];
        #pragma unroll
        for (int d = 0; d < 4; ++d) {
          const int src = ((sq2 + (d >> 1)) << 4) + c;
          const int v0 = __shfl((int)pk0[d & 1], src);
          const int v1 = __shfl((int)pk1[d & 1], src);
          dw[d] = (Q >= 2) ? v1 : v0;
        }
        int4 bi = make_int4(dw[0], dw[1], dw[2], dw[3]);
        pb[kc] = *(bf16x8*)&bi;
      }

      // ---- O^T += V^T . P^T  (2 key-chunks x 4 d-chunks) ----
      #pragma unroll
      for (int ch = 0; ch < 4; ++ch)
        #pragma unroll
        for (int t2 = 0; t2 < 4; ++t2) o[ch][t2] *= alpha;
      #pragma unroll
      for (int kc = 0; kc < 2; ++kc) {
        if (k0 + kc * 32 <= mylastk) {
          #pragma unroll
          for (int ch = 0; ch < 4; ++ch) {
            bf16x8 af =
                *(const bf16x8*)&Vt[half][(ch * 16 + c) * 72 + kc * 32 + Q * 8];
            o[ch] = __builtin_amdgcn_mfma_f32_16x16x32_bf16(af, pb[kc], o[ch],
                                                            0, 0, 0);
          }
        }
      }
    }
  }

  // ---- merge the two key-half partials (LDS, intra-block) ----
  __syncthreads();                       // all K/V LDS reads done; reuse it
  float* obuf = (float*)&Ks[0][0];       // [4 waves][64 lanes][stride 17] f32
  float* mlb  = (float*)&Vt[0][0];       // [4 waves][32] f32 (m then l)
  if (half && nqw > 0) {
    float* ob = &obuf[(wq * 64 + lane) * 17];   // stride 17: conflict-free
    #pragma unroll
    for (int ch = 0; ch < 4; ++ch)
      #pragma unroll
      for (int t2 = 0; t2 < 4; ++t2) ob[ch * 4 + t2] = o[ch][t2];
    if (Q == 0) { mlb[wq * 32 + c] = m_run; mlb[wq * 32 + 16 + c] = l_run; }
  }
  __syncthreads();

  // ---- epilogue: O[q][d] = (wA*oA + wB*oB)[d][q] / L  (waves 0-3) ----
  if (!half && nqw > 0 && c < nqw) {
    const float mB = mlb[wq * 32 + c];
    const float lB = mlb[wq * 32 + 16 + c];
    const float M  = fmaxf(m_run, mB);
    const float wA = __expf(m_run - M);   // exp(-3e38 - M) == 0 handles empty
    const float wB = __expf(mB - M);      // halves / fully-masked partials
    const float invl = 1.f / (wA * l_run + wB * lB);
    const float* ob = &obuf[(wq * 64 + lane) * 17];
    const int tok = r + (q0 + qb + c) * p;
    unsigned int* dst =
        (unsigned int*)(ao + (size_t)(b * T_ + tok) * D_ + h * HD_);
    #pragma unroll
    for (int ch = 0; ch < 4; ++ch)
      #pragma unroll
      for (int rp = 0; rp < 2; ++rp) {
        const int dhalf = ch * 16 + Q * 4 + rp * 2;   // even
        const float v0 =
            (wA * o[ch][rp * 2]     + wB * ob[ch * 4 + rp * 2])     * invl;
        const float v1 =
            (wA * o[ch][rp * 2 + 1] + wB * ob[ch * 4 + rp * 2 + 1]) * invl;
        dst[dhalf >> 1] = pack2bf(v0, v1);
      }
  }
}

// ---------------------------------------------------------------------------
extern "C" void kernel_launch(void* const* d_in, const int* in_sizes, int n_in,
                              void* d_out, int out_size, void* d_ws, size_t ws_size,
                              hipStream_t stream) {
  const float* x      = (const float*)d_in[0];   // (B,T,D)
  const int*   period = (const int*)  d_in[1];   // (B,H)
  const float* w_qkv  = (const float*)d_in[2];   // (3D, D)
  const float* b_qkv  = (const float*)d_in[3];   // (3D,)
  const float* w_out  = (const float*)d_in[4];   // (D, D)
  const float* b_out  = (const float*)d_in[5];   // (D,)
  float* out = (float*)d_out;                    // (B,T,D)

  const int M = B_ * T_;                         // 4096

  // ws layout: qkvb [0,12 MB) bf16, aob [12,16 MB) bf16
  char* ws = (char*)d_ws;
  unsigned short* qkvb = (unsigned short*)(ws);
  unsigned short* aob  = (unsigned short*)(ws + (size_t)M * QKVS * 2);

  // 1) QKV projection straight from fp32 inputs -> bf16 token-major qkvb
  gemm_qkv_f32<<<dim3(QKVS / 64, M / 128), dim3(256), 0, stream>>>(
      x, w_qkv, b_qkv, qkvb, M, QKVS, D_);

  // 2) residue-class flash attention, split-K halves (512 threads) -> aob
  attn_flash4<<<dim3(16, 63), dim3(512), 0, stream>>>(qkvb, period, aob);

  // 3) output projection (A bf16, B fp32) -> fp32 out
  gemm_out_mix<<<dim3(D_ / 64, M / 128), dim3(256), 0, stream>>>(
      aob, w_out, b_out, out, M, D_, D_);
}

// Round 4
// 109.069 us; speedup vs baseline: 1.8192x; 1.0238x over previous
//
#include <hip/hip_runtime.h>
#include <math.h>

#define B_  2
#define T_  2048
#define D_  512
#define H_  8
#define HD_ 64
#define QKVS (3*D_)   // 1536

typedef __bf16 bf16x8 __attribute__((ext_vector_type(8)));
typedef float  f32x4  __attribute__((ext_vector_type(4)));

__device__ inline unsigned short f2bf(float f) {   // RN-even fp32->bf16
  unsigned int u = __float_as_uint(f);
  return (unsigned short)((u + 0x7FFFu + ((u >> 16) & 1u)) >> 16);
}
__device__ inline unsigned int pack2bf(float lo, float hi) {
  return (unsigned int)f2bf(lo) | ((unsigned int)f2bf(hi) << 16);
}

// 8 fp32 -> bf16x8 (compiler emits v_cvt_pk_bf16_f32 pairs, RNE)
__device__ inline bf16x8 cvt8r(float4 a, float4 b) {
  bf16x8 r;
  r[0] = (__bf16)a.x; r[1] = (__bf16)a.y; r[2] = (__bf16)a.z; r[3] = (__bf16)a.w;
  r[4] = (__bf16)b.x; r[5] = (__bf16)b.y; r[6] = (__bf16)b.z; r[7] = (__bf16)b.w;
  return r;
}

// ---------------------------------------------------------------------------
// MFMA bf16 GEMM (NT), 128x64 tile, BK=128 (4 x 32-K panels per barrier
// round), LDS 48 KB bf16 -> 3 blocks/CU. MFMA phase byte-identical to the
// verified 107.5us kernel. Staging differs by operand dtype:
//   AF32=1: A is fp32 -> reg-staged (global f32 -> cvt_pk -> ds_write_b128
//           in LDS-LINEAR lane order: same conflict-free pattern as
//           global_load_lds). Used by GEMM1 (A = x).
//   AF32=0: A is bf16 -> global_load_lds direct (proven path). GEMM2.
//   B (weights) is always fp32 -> reg-staged the same way.
// This deletes the standalone cast kernel entirely.
// ---------------------------------------------------------------------------
template<int AF32, int BF16OUT>
__global__ __launch_bounds__(256, 3)
void gemm_nt_fused(const void* __restrict__ Av,
                   const float* __restrict__ Bw,
                   const float* __restrict__ bias, void* __restrict__ Cv,
                   int M, int N, int K) {
  __shared__ __align__(16) short Asd[4][128 * 32];   // 4 x 8 KB
  __shared__ __align__(16) short Bsd[4][64 * 32];    // 4 x 4 KB

  const int tid = threadIdx.x;
  const int w   = tid >> 6;
  const int l   = tid & 63;
  const int wr  = w >> 1;
  const int wc  = w & 1;
  const int q   = l >> 4;
  const int ml  = l & 15;
  const int arow = l >> 2;          // gload_lds A path (AF32=0)
  const int kch  = (l & 3) * 8;

  // reg-staging assignment: LDS-linear slot s -> row s>>2, k-chunk (s&3)*8
  const int rs_row = tid >> 2;
  const int rs_k   = (tid & 3) * 8;

  // bijective XCD swizzle (both grids are multiples of 8): consecutive
  // blocks (same A row-panel) stay on one XCD's L2.
  int flat = blockIdx.y * gridDim.x + blockIdx.x;
  const int nb = gridDim.x * gridDim.y;
  flat = (flat & 7) * (nb >> 3) + (flat >> 3);
  const int bx = flat % gridDim.x, by = flat / gridDim.x;
  const int rowbase = by * 128;
  const int colbase = bx * 64;

  const float*          Af = (const float*)Av;
  const unsigned short* Ab = (const unsigned short*)Av;

  f32x4 acc[4][2] = {};

  for (int k0 = 0; k0 < K; k0 += 128) {
    __syncthreads();
    #pragma unroll
    for (int pnl = 0; pnl < 4; ++pnl) {
      const int kp = k0 + pnl * 32;
      if (AF32) {
        // ---- A: 128x32 fp32 -> bf16, two LDS-linear slots per thread ----
        #pragma unroll
        for (int j = 0; j < 2; ++j) {
          const int s   = j * 256 + tid;
          const int row = s >> 2, ko = (s & 3) * 8;
          const float* g = Af + (size_t)(rowbase + row) * K + kp + ko;
          float4 v0 = ((const float4*)g)[0];
          float4 v1 = ((const float4*)g)[1];
          *(bf16x8*)&Asd[pnl][s * 8] = cvt8r(v0, v1);
        }
      } else {
        // ---- A: 128x32 bf16 via global_load_lds (2 issues, proven) ----
        #pragma unroll
        for (int s = 0; s < 2; ++s) {
          const unsigned short* g =
              Ab + (size_t)(rowbase + s * 64 + w * 16 + arow) * K + kp + kch;
          __builtin_amdgcn_global_load_lds(
              (const __attribute__((address_space(1))) void*)g,
              (__attribute__((address_space(3))) void*)
                  &Asd[pnl][s * 2048 + w * 512], 16, 0, 0);
        }
      }
      // ---- B: 64x32 fp32 -> bf16, one LDS-linear slot per thread ----
      {
        const float* g = Bw + (size_t)(colbase + rs_row) * K + kp + rs_k;
        float4 v0 = ((const float4*)g)[0];
        float4 v1 = ((const float4*)g)[1];
        *(bf16x8*)&Bsd[pnl][tid * 8] = cvt8r(v0, v1);
      }
    }
    __syncthreads();

    #pragma unroll
    for (int pnl = 0; pnl < 4; ++pnl) {
      bf16x8 af[4], bfr[2];
      #pragma unroll
      for (int mi = 0; mi < 4; ++mi)
        af[mi] = *(const bf16x8*)&Asd[pnl][(wr * 64 + mi * 16 + ml) * 32 + q * 8];
      #pragma unroll
      for (int ni = 0; ni < 2; ++ni)
        bfr[ni] = *(const bf16x8*)&Bsd[pnl][(wc * 32 + ni * 16 + ml) * 32 + q * 8];
      #pragma unroll
      for (int mi = 0; mi < 4; ++mi)
        #pragma unroll
        for (int ni = 0; ni < 2; ++ni)
          acc[mi][ni] = __builtin_amdgcn_mfma_f32_16x16x32_bf16(
              af[mi], bfr[ni], acc[mi][ni], 0, 0, 0);
    }
  }

  #pragma unroll
  for (int mi = 0; mi < 4; ++mi) {
    #pragma unroll
    for (int ni = 0; ni < 2; ++ni) {
      const int col = colbase + wc * 32 + ni * 16 + ml;
      const float bv = bias[col];
      #pragma unroll
      for (int r = 0; r < 4; ++r) {
        const int row = rowbase + wr * 64 + mi * 16 + q * 4 + r;
        const float val = acc[mi][ni][r] + bv;
        if (BF16OUT)
          ((unsigned short*)Cv)[(size_t)row * N + col] = f2bf(val);
        else
          ((float*)Cv)[(size_t)row * N + col] = val;
      }
    }
  }
}

// ---------------------------------------------------------------------------
// Residue-class flash attention, 64-query stripes, SPLIT-K across wave halves
// (unchanged from the verified 107.5 us version).
// ---------------------------------------------------------------------------
__global__ __launch_bounds__(512)
void attn_flash4(const unsigned short* __restrict__ qkv,
                 const int* __restrict__ periods,
                 unsigned short* __restrict__ ao) {
  const int bh = blockIdx.x, slot = 62 - blockIdx.y;   // heavy-first
  int p = periods[bh]; if (p < 1) p = 1;
  const int g  = slot / p;
  const int r  = slot - g * p;
  const int L  = (T_ - 1 - r) / p + 1;   // tokens in this residue class
  const int q0 = g << 6;                 // stripe base (t-space)
  if (q0 >= L) return;
  const int b = bh >> 3, h = bh & 7;
  const int Lrem = L - q0;               // >= 1
  const int Nkb  = min(L, q0 + 64);      // keys needed by the whole stripe

  const int tid  = threadIdx.x;
  const int w    = tid >> 6;             // wave 0..7
  const int wq   = w & 3;                // query sub-tile id (shared by halves)
  const int half = tid >> 8;             // key-split half: 0 or 1
  const int tl   = tid & 255;            // thread id within the half
  const int lane = tid & 63;
  const int Q = lane >> 4, c = lane & 15;

  __shared__ __align__(16) unsigned short Qs[64 * 72];       // 9216 B
  __shared__ __align__(16) unsigned short Ks[2][64 * 72];    // 2 x 9216 B
  __shared__ __align__(16) unsigned short Vt[2][64 * 72];    // 2 x 9216 B, [d][key]

  const size_t rowb = (size_t)b * T_ * QKVS + (size_t)h * HD_;

  // ---- stage Q stripe (64 rows x 64 halfs): 16 B per thread, 512 threads ----
  {
    const int u = tid >> 3, ch4 = (tid & 7) * 8;
    const int t = q0 + min(u, Lrem - 1);            // clamp (dup row, masked)
    const unsigned short* gq = qkv + rowb + (size_t)(r + t * p) * QKVS + ch4;
    *(int4*)&Qs[u * 72 + ch4] = *(const int4*)gq;
  }
  __syncthreads();
  bf16x8 qf[2];                          // B-frag: B[k=d=Q*8+j(+32)][n=q=c]
  qf[0] = *(const bf16x8*)&Qs[(wq * 16 + c) * 72 + Q * 8];
  qf[1] = *(const bf16x8*)&Qs[(wq * 16 + c) * 72 + Q * 8 + 32];

  const int qb      = wq * 16;           // wave's query offset in stripe
  const int nqw     = min(16, Lrem - qb);// <=0 -> inactive wave (barriers only)
  const int qglob   = q0 + qb + c;       // this lane's query t-index
  const int mylastk = q0 + qb + 15;      // last key this wave can need

  float m_run = -3.0e38f, l_run = 0.f;
  f32x4 o[4] = {};
  const size_t kb = rowb + D_;
  const size_t vb = rowb + 2 * D_;

  // staging assignments (per 256-thread half, 64-key tiles)
  const int krow = tl >> 2, koff = (tl & 3) * 16;      // K: 2x16B/thread
  const int vkey = tl & 63, vd0 = ((tl >> 6) & 3) * 8; // V: 2x16B/thread

  // key-range split: half 0 -> rounds [0, RA), half 1 -> rounds [RA, R)
  const int R     = (Nkb + 63) >> 6;     // total 64-key rounds
  const int RA    = (R + 1) >> 1;        // rounds for half 0 (>= half 1's)
  const int myR   = half ? (R - RA) : RA;
  const int kbase = half ? (RA << 6) : 0;

  // ---- prefetch this half's round 0 ----
  int4 kp0, kp1, vp0, vp1;
  if (myR > 0) {
    const int tk = min(kbase + krow, Nkb - 1);
    const int tv = min(kbase + vkey, Nkb - 1);
    const unsigned short* gk = qkv + kb + (size_t)(r + tk * p) * QKVS + koff;
    const unsigned short* gv = qkv + vb + (size_t)(r + tv * p) * QKVS;
    kp0 = ((const int4*)gk)[0];
    kp1 = ((const int4*)gk)[1];
    vp0 = *(const int4*)(gv + vd0);
    vp1 = *(const int4*)(gv + vd0 + 32);
  }

  // uniform trip count (RA >= myR for both halves) -> barriers never diverge
  for (int rr = 0; rr < RA; ++rr) {
    const int k0 = kbase + (rr << 6);    // absolute key base of this round
    __syncthreads();                     // prev round's frag reads complete
    if (rr < myR) {
      // ---- commit prefetched K (row-major) + V (transposed) ----
      *(int4*)&Ks[half][krow * 72 + koff + 0] = kp0;
      *(int4*)&Ks[half][krow * 72 + koff + 8] = kp1;
      unsigned short vh0[8], vh1[8];
      *(int4*)vh0 = vp0;
      *(int4*)vh1 = vp1;
      #pragma unroll
      for (int j = 0; j < 8; ++j) {
        Vt[half][(vd0 + j) * 72 + vkey]      = vh0[j];
        Vt[half][(vd0 + 32 + j) * 72 + vkey] = vh1[j];
      }
    }
    __syncthreads();                     // LDS valid

    // ---- issue next round's global loads (hide behind compute) ----
    if (rr + 1 < myR) {
      const int tk = min(k0 + 64 + krow, Nkb - 1);
      const int tv = min(k0 + 64 + vkey, Nkb - 1);
      const unsigned short* gk = qkv + kb + (size_t)(r + tk * p) * QKVS + koff;
      const unsigned short* gv = qkv + vb + (size_t)(r + tv * p) * QKVS;
      kp0 = ((const int4*)gk)[0];
      kp1 = ((const int4*)gk)[1];
      vp0 = *(const int4*)(gv + vd0);
      vp1 = *(const int4*)(gv + vd0 + 32);
    }

    if (rr < myR && nqw > 0 && k0 <= mylastk) {
      // ---- S^T tiles (4 x 16 keys), per-tile skip ----
      float pvv[16];
      float tmax = -3.0e38f;
      #pragma unroll
      for (int mt = 0; mt < 4; ++mt) {
        if (k0 + mt * 16 <= mylastk) {
          bf16x8 a0 = *(const bf16x8*)&Ks[half][(mt * 16 + c) * 72 + Q * 8];
          bf16x8 a1 = *(const bf16x8*)&Ks[half][(mt * 16 + c) * 72 + Q * 8 + 32];
          f32x4 s = {};
          s = __builtin_amdgcn_mfma_f32_16x16x32_bf16(a0, qf[0], s, 0, 0, 0);
          s = __builtin_amdgcn_mfma_f32_16x16x32_bf16(a1, qf[1], s, 0, 0, 0);
          #pragma unroll
          for (int rg = 0; rg < 4; ++rg) {
            const int kk = k0 + mt * 16 + Q * 4 + rg;   // key t-index
            float v = s[rg] * 0.125f;                   // 1/sqrt(HD)
            v = (kk <= qglob) ? v : -3.0e38f;
            pvv[mt * 4 + rg] = v;
            tmax = fmaxf(tmax, v);
          }
        } else {
          #pragma unroll
          for (int rg = 0; rg < 4; ++rg) pvv[mt * 4 + rg] = -3.0e38f;
        }
      }

      // ---- online softmax per column (q = c) ----
      tmax = fmaxf(tmax, __shfl_xor(tmax, 16));
      tmax = fmaxf(tmax, __shfl_xor(tmax, 32));
      const float m_new = fmaxf(m_run, tmax);
      const float alpha = __expf(m_run - m_new);
      float tsum = 0.f;
      #pragma unroll
      for (int i = 0; i < 16; ++i) {
        pvv[i] = __expf(pvv[i] - m_new);
        tsum += pvv[i];
      }
      tsum += __shfl_xor(tsum, 16);
      tsum += __shfl_xor(tsum, 32);
      l_run = l_run * alpha + tsum;
      m_run = m_new;

      // ---- P^T -> B-operand frags per 32-key chunk ----
      bf16x8 pb[2];
      const int sq2 = (Q & 1) << 1;
      #pragma unroll
      for (int kc = 0; kc < 2; ++kc) {
        unsigned int pk0[2], pk1[2];
        pk0[0] = pack2bf(pvv[kc * 8 + 0], pvv[kc * 8 + 1]);
        pk0[1] = pack2bf(pvv[kc * 8 + 2], pvv[kc * 8 + 3]);
        pk1[0] = pack2bf(pvv[kc * 8 + 4], pvv[kc * 8 + 5]);
        pk1[1] = pack2bf(pvv[kc * 8 + 6], pvv[kc * 8 + 7]);
        int dw[4];
        #pragma unroll
        for (int d = 0; d < 4; ++d) {
          const int src = ((sq2 + (d >> 1)) << 4) + c;
          const int v0 = __shfl((int)pk0[d & 1], src);
          const int v1 = __shfl((int)pk1[d & 1], src);
          dw[d] = (Q >= 2) ? v1 : v0;
        }
        int4 bi = make_int4(dw[0], dw[1], dw[2], dw[3]);
        pb[kc] = *(bf16x8*)&bi;
      }

      // ---- O^T += V^T . P^T  (2 key-chunks x 4 d-chunks) ----
      #pragma unroll
      for (int ch = 0; ch < 4; ++ch)
        #pragma unroll
        for (int t2 = 0; t2 < 4; ++t2) o[ch][t2] *= alpha;
      #pragma unroll
      for (int kc = 0; kc < 2; ++kc) {
        if (k0 + kc * 32 <= mylastk) {
          #pragma unroll
          for (int ch = 0; ch < 4; ++ch) {
            bf16x8 af =
                *(const bf16x8*)&Vt[half][(ch * 16 + c) * 72 + kc * 32 + Q * 8];
            o[ch] = __builtin_amdgcn_mfma_f32_16x16x32_bf16(af, pb[kc], o[ch],
                                                            0, 0, 0);
          }
        }
      }
    }
  }

  // ---- merge the two key-half partials (LDS, intra-block) ----
  __syncthreads();                       // all K/V LDS reads done; reuse it
  float* obuf = (float*)&Ks[0][0];       // [4 waves][64 lanes][stride 17] f32
  float* mlb  = (float*)&Vt[0][0];       // [4 waves][32] f32 (m then l)
  if (half && nqw > 0) {
    float* ob = &obuf[(wq * 64 + lane) * 17];   // stride 17: conflict-free
    #pragma unroll
    for (int ch = 0; ch < 4; ++ch)
      #pragma unroll
      for (int t2 = 0; t2 < 4; ++t2) ob[ch * 4 + t2] = o[ch][t2];
    if (Q == 0) { mlb[wq * 32 + c] = m_run; mlb[wq * 32 + 16 + c] = l_run; }
  }
  __syncthreads();

  // ---- epilogue: O[q][d] = (wA*oA + wB*oB)[d][q] / L  (waves 0-3) ----
  if (!half && nqw > 0 && c < nqw) {
    const float mB = mlb[wq * 32 + c];
    const float lB = mlb[wq * 32 + 16 + c];
    const float M  = fmaxf(m_run, mB);
    const float wA = __expf(m_run - M);   // exp(-3e38 - M) == 0 handles empty
    const float wB = __expf(mB - M);      // halves / fully-masked partials
    const float invl = 1.f / (wA * l_run + wB * lB);
    const float* ob = &obuf[(wq * 64 + lane) * 17];
    const int tok = r + (q0 + qb + c) * p;
    unsigned int* dst =
        (unsigned int*)(ao + (size_t)(b * T_ + tok) * D_ + h * HD_);
    #pragma unroll
    for (int ch = 0; ch < 4; ++ch)
      #pragma unroll
      for (int rp = 0; rp < 2; ++rp) {
        const int dhalf = ch * 16 + Q * 4 + rp * 2;   // even
        const float v0 =
            (wA * o[ch][rp * 2]     + wB * ob[ch * 4 + rp * 2])     * invl;
        const float v1 =
            (wA * o[ch][rp * 2 + 1] + wB * ob[ch * 4 + rp * 2 + 1]) * invl;
        dst[dhalf >> 1] = pack2bf(v0, v1);
      }
  }
}

// ---------------------------------------------------------------------------
extern "C" void kernel_launch(void* const* d_in, const int* in_sizes, int n_in,
                              void* d_out, int out_size, void* d_ws, size_t ws_size,
                              hipStream_t stream) {
  const float* x      = (const float*)d_in[0];   // (B,T,D)
  const int*   period = (const int*)  d_in[1];   // (B,H)
  const float* w_qkv  = (const float*)d_in[2];   // (3D, D)
  const float* b_qkv  = (const float*)d_in[3];   // (3D,)
  const float* w_out  = (const float*)d_in[4];   // (D, D)
  const float* b_out  = (const float*)d_in[5];   // (D,)
  float* out = (float*)d_out;                    // (B,T,D)

  const int M = B_ * T_;                         // 4096

  // ws layout: qkvb [0,12 MB) bf16, aob [12,16 MB) bf16
  char* ws = (char*)d_ws;
  unsigned short* qkvb = (unsigned short*)(ws);
  unsigned short* aob  = (unsigned short*)(ws + (size_t)M * QKVS * 2);

  // 1) QKV projection straight from fp32 inputs (A reg-staged cvt, B
  //    reg-staged cvt) -> bf16 token-major qkvb
  gemm_nt_fused<1, 1><<<dim3(QKVS / 64, M / 128), dim3(256), 0, stream>>>(
      x, w_qkv, b_qkv, qkvb, M, QKVS, D_);

  // 2) residue-class flash attention, split-K halves (512 threads) -> aob
  attn_flash4<<<dim3(16, 63), dim3(512), 0, stream>>>(qkvb, period, aob);

  // 3) output projection (A bf16 via gload_lds, B=w_out fp32 reg-staged)
  //    -> fp32 out
  gemm_nt_fused<0, 0><<<dim3(D_ / 64, M / 128), dim3(256), 0, stream>>>(
      aob, w_out, b_out, out, M, D_, D_);
}

// Round 5
// 106.750 us; speedup vs baseline: 1.8588x; 1.0217x over previous
//
#include <hip/hip_runtime.h>
#include <math.h>

#define B_  2
#define T_  2048
#define D_  512
#define H_  8
#define HD_ 64
#define QKVS (3*D_)   // 1536

typedef __bf16 bf16x8 __attribute__((ext_vector_type(8)));
typedef float  f32x4  __attribute__((ext_vector_type(4)));

__device__ inline unsigned short f2bf(float f) {   // RN-even fp32->bf16
  unsigned int u = __float_as_uint(f);
  return (unsigned short)((u + 0x7FFFu + ((u >> 16) & 1u)) >> 16);
}
__device__ inline unsigned int pack2bf(float lo, float hi) {
  return (unsigned int)f2bf(lo) | ((unsigned int)f2bf(hi) << 16);
}

// ---------------------------------------------------------------------------
// Fused cast fp32 -> bf16 for x, w_qkv, w_out in one launch (float4 units).
// 19 MB of traffic at HBM BW ~= 3 us: this is the cheapest way to feed the
// gload_lds bf16 GEMM path (R3/R4 measured: fusing the cast into the GEMMs
// via fp32-LDS or reg-staged cvt loses 1.5-4.2 us vs this).
// ---------------------------------------------------------------------------
__global__ void cast_all(const float* __restrict__ x,
                         const float* __restrict__ wq,
                         const float* __restrict__ wo,
                         unsigned short* __restrict__ xb,
                         unsigned short* __restrict__ wqb,
                         unsigned short* __restrict__ wob) {
  const int n_x  = (B_ * T_ * D_) / 4;
  const int n_wq = (QKVS * D_) / 4;
  const int n_wo = (D_ * D_) / 4;
  int i = blockIdx.x * blockDim.x + threadIdx.x;
  const float* src; unsigned short* dst; int off;
  if (i < n_x)                    { src = x;  dst = xb;  off = i; }
  else if (i < n_x + n_wq)        { src = wq; dst = wqb; off = i - n_x; }
  else if (i < n_x + n_wq + n_wo) { src = wo; dst = wob; off = i - n_x - n_wq; }
  else return;
  float4 v = ((const float4*)src)[off];
  ushort4 o;
  o.x = f2bf(v.x); o.y = f2bf(v.y); o.z = f2bf(v.z); o.w = f2bf(v.w);
  ((ushort4*)dst)[off] = o;
}

// ---------------------------------------------------------------------------
// MFMA bf16 GEMM (NT), 128x64 tile, BK=128 via FOUR 32-K panels per barrier
// round (per-panel global_load_lds lane mapping identical to the proven
// BK=32 scheme). ONE barrier pair per 128 K -> 4 rounds for K=512.
// LDS = 4 x 12 KB = 48 KB -> 3 blocks/CU. 4 waves, 4x2 accs each.
// ~760 TF on GEMM1's shape = ~85% of this structure's ceiling (m97 ~900).
// ---------------------------------------------------------------------------
template<int BF16OUT>
__global__ __launch_bounds__(256, 3)
void gemm_nt_bk128(const unsigned short* __restrict__ A,
                   const unsigned short* __restrict__ Bw,
                   const float* __restrict__ bias, void* __restrict__ Cv,
                   int M, int N, int K) {
  __shared__ short Asd[4][128 * 32];   // 4 x 8 KB
  __shared__ short Bsd[4][64 * 32];    // 4 x 4 KB

  const int tid = threadIdx.x;
  const int w   = tid >> 6;
  const int l   = tid & 63;
  const int wr  = w >> 1;
  const int wc  = w & 1;
  const int q   = l >> 4;
  const int ml  = l & 15;
  const int arow = l >> 2;
  const int kch  = (l & 3) * 8;

  const int rowbase = blockIdx.y * 128;
  const int colbase = blockIdx.x * 64;

  f32x4 acc[4][2] = {};

  for (int k0 = 0; k0 < K; k0 += 128) {
    __syncthreads();
    #pragma unroll
    for (int pnl = 0; pnl < 4; ++pnl) {
      const int kp = k0 + pnl * 32;
      #pragma unroll
      for (int s = 0; s < 2; ++s) {
        const unsigned short* g =
            A + (size_t)(rowbase + s * 64 + w * 16 + arow) * K + kp + kch;
        __builtin_amdgcn_global_load_lds(
            (const __attribute__((address_space(1))) void*)g,
            (__attribute__((address_space(3))) void*)
                &Asd[pnl][s * 2048 + w * 512], 16, 0, 0);
      }
      const unsigned short* g =
          Bw + (size_t)(colbase + w * 16 + arow) * K + kp + kch;
      __builtin_amdgcn_global_load_lds(
          (const __attribute__((address_space(1))) void*)g,
          (__attribute__((address_space(3))) void*)&Bsd[pnl][w * 512],
          16, 0, 0);
    }
    __syncthreads();

    #pragma unroll
    for (int pnl = 0; pnl < 4; ++pnl) {
      bf16x8 af[4], bfr[2];
      #pragma unroll
      for (int mi = 0; mi < 4; ++mi)
        af[mi] = *(const bf16x8*)&Asd[pnl][(wr * 64 + mi * 16 + ml) * 32 + q * 8];
      #pragma unroll
      for (int ni = 0; ni < 2; ++ni)
        bfr[ni] = *(const bf16x8*)&Bsd[pnl][(wc * 32 + ni * 16 + ml) * 32 + q * 8];
      #pragma unroll
      for (int mi = 0; mi < 4; ++mi)
        #pragma unroll
        for (int ni = 0; ni < 2; ++ni)
          acc[mi][ni] = __builtin_amdgcn_mfma_f32_16x16x32_bf16(
              af[mi], bfr[ni], acc[mi][ni], 0, 0, 0);
    }
  }

  #pragma unroll
  for (int mi = 0; mi < 4; ++mi) {
    #pragma unroll
    for (int ni = 0; ni < 2; ++ni) {
      const int col = colbase + wc * 32 + ni * 16 + ml;
      const float bv = bias[col];
      #pragma unroll
      for (int r = 0; r < 4; ++r) {
        const int row = rowbase + wr * 64 + mi * 16 + q * 4 + r;
        const float val = acc[mi][ni][r] + bv;
        if (BF16OUT)
          ((unsigned short*)Cv)[(size_t)row * N + col] = f2bf(val);
        else
          ((float*)Cv)[(size_t)row * N + col] = val;
      }
    }
  }
}

// ---------------------------------------------------------------------------
// Residue-class flash attention, 64-query stripes, SPLIT-K across wave halves:
// 8 waves / 512 threads. Waves 0-3 process keys [0, RA*64), waves 4-7 process
// [RA*64, Nkb) of the SAME query stripe, each half with private K/V LDS.
// Online-softmax partials (m, l, o) merged through LDS at the end.
// ---------------------------------------------------------------------------
__global__ __launch_bounds__(512)
void attn_flash4(const unsigned short* __restrict__ qkv,
                 const int* __restrict__ periods,
                 unsigned short* __restrict__ ao) {
  const int bh = blockIdx.x, slot = 62 - blockIdx.y;   // heavy-first
  int p = periods[bh]; if (p < 1) p = 1;
  const int g  = slot / p;
  const int r  = slot - g * p;
  const int L  = (T_ - 1 - r) / p + 1;   // tokens in this residue class
  const int q0 = g << 6;                 // stripe base (t-space)
  if (q0 >= L) return;
  const int b = bh >> 3, h = bh & 7;
  const int Lrem = L - q0;               // >= 1
  const int Nkb  = min(L, q0 + 64);      // keys needed by the whole stripe

  const int tid  = threadIdx.x;
  const int w    = tid >> 6;             // wave 0..7
  const int wq   = w & 3;                // query sub-tile id (shared by halves)
  const int half = tid >> 8;             // key-split half: 0 or 1
  const int tl   = tid & 255;            // thread id within the half
  const int lane = tid & 63;
  const int Q = lane >> 4, c = lane & 15;

  __shared__ __align__(16) unsigned short Qs[64 * 72];       // 9216 B
  __shared__ __align__(16) unsigned short Ks[2][64 * 72];    // 2 x 9216 B
  __shared__ __align__(16) unsigned short Vt[2][64 * 72];    // 2 x 9216 B, [d][key]

  const size_t rowb = (size_t)b * T_ * QKVS + (size_t)h * HD_;

  // ---- stage Q stripe (64 rows x 64 halfs): 16 B per thread, 512 threads ----
  {
    const int u = tid >> 3, ch4 = (tid & 7) * 8;
    const int t = q0 + min(u, Lrem - 1);            // clamp (dup row, masked)
    const unsigned short* gq = qkv + rowb + (size_t)(r + t * p) * QKVS + ch4;
    *(int4*)&Qs[u * 72 + ch4] = *(const int4*)gq;
  }
  __syncthreads();
  bf16x8 qf[2];                          // B-frag: B[k=d=Q*8+j(+32)][n=q=c]
  qf[0] = *(const bf16x8*)&Qs[(wq * 16 + c) * 72 + Q * 8];
  qf[1] = *(const bf16x8*)&Qs[(wq * 16 + c) * 72 + Q * 8 + 32];

  const int qb      = wq * 16;           // wave's query offset in stripe
  const int nqw     = min(16, Lrem - qb);// <=0 -> inactive wave (barriers only)
  const int qglob   = q0 + qb + c;       // this lane's query t-index
  const int mylastk = q0 + qb + 15;      // last key this wave can need

  float m_run = -3.0e38f, l_run = 0.f;
  f32x4 o[4] = {};
  const size_t kb = rowb + D_;
  const size_t vb = rowb + 2 * D_;

  // staging assignments (per 256-thread half, 64-key tiles)
  const int krow = tl >> 2, koff = (tl & 3) * 16;      // K: 2x16B/thread
  const int vkey = tl & 63, vd0 = ((tl >> 6) & 3) * 8; // V: 2x16B/thread

  // key-range split: half 0 -> rounds [0, RA), half 1 -> rounds [RA, R)
  const int R     = (Nkb + 63) >> 6;     // total 64-key rounds
  const int RA    = (R + 1) >> 1;        // rounds for half 0 (>= half 1's)
  const int myR   = half ? (R - RA) : RA;
  const int kbase = half ? (RA << 6) : 0;

  // ---- prefetch this half's round 0 ----
  int4 kp0, kp1, vp0, vp1;
  if (myR > 0) {
    const int tk = min(kbase + krow, Nkb - 1);
    const int tv = min(kbase + vkey, Nkb - 1);
    const unsigned short* gk = qkv + kb + (size_t)(r + tk * p) * QKVS + koff;
    const unsigned short* gv = qkv + vb + (size_t)(r + tv * p) * QKVS;
    kp0 = ((const int4*)gk)[0];
    kp1 = ((const int4*)gk)[1];
    vp0 = *(const int4*)(gv + vd0);
    vp1 = *(const int4*)(gv + vd0 + 32);
  }

  // uniform trip count (RA >= myR for both halves) -> barriers never diverge
  for (int rr = 0; rr < RA; ++rr) {
    const int k0 = kbase + (rr << 6);    // absolute key base of this round
    __syncthreads();                     // prev round's frag reads complete
    if (rr < myR) {
      // ---- commit prefetched K (row-major) + V (transposed) ----
      *(int4*)&Ks[half][krow * 72 + koff + 0] = kp0;
      *(int4*)&Ks[half][krow * 72 + koff + 8] = kp1;
      unsigned short vh0[8], vh1[8];
      *(int4*)vh0 = vp0;
      *(int4*)vh1 = vp1;
      #pragma unroll
      for (int j = 0; j < 8; ++j) {
        Vt[half][(vd0 + j) * 72 + vkey]      = vh0[j];
        Vt[half][(vd0 + 32 + j) * 72 + vkey] = vh1[j];
      }
    }
    __syncthreads();                     // LDS valid

    // ---- issue next round's global loads (hide behind compute) ----
    if (rr + 1 < myR) {
      const int tk = min(k0 + 64 + krow, Nkb - 1);
      const int tv = min(k0 + 64 + vkey, Nkb - 1);
      const unsigned short* gk = qkv + kb + (size_t)(r + tk * p) * QKVS + koff;
      const unsigned short* gv = qkv + vb + (size_t)(r + tv * p) * QKVS;
      kp0 = ((const int4*)gk)[0];
      kp1 = ((const int4*)gk)[1];
      vp0 = *(const int4*)(gv + vd0);
      vp1 = *(const int4*)(gv + vd0 + 32);
    }

    if (rr < myR && nqw > 0 && k0 <= mylastk) {
      // ---- S^T tiles (4 x 16 keys), per-tile skip ----
      float pvv[16];
      float tmax = -3.0e38f;
      #pragma unroll
      for (int mt = 0; mt < 4; ++mt) {
        if (k0 + mt * 16 <= mylastk) {
          bf16x8 a0 = *(const bf16x8*)&Ks[half][(mt * 16 + c) * 72 + Q * 8];
          bf16x8 a1 = *(const bf16x8*)&Ks[half][(mt * 16 + c) * 72 + Q * 8 + 32];
          f32x4 s = {};
          s = __builtin_amdgcn_mfma_f32_16x16x32_bf16(a0, qf[0], s, 0, 0, 0);
          s = __builtin_amdgcn_mfma_f32_16x16x32_bf16(a1, qf[1], s, 0, 0, 0);
          #pragma unroll
          for (int rg = 0; rg < 4; ++rg) {
            const int kk = k0 + mt * 16 + Q * 4 + rg;   // key t-index
            float v = s[rg] * 0.125f;                   // 1/sqrt(HD)
            v = (kk <= qglob) ? v : -3.0e38f;
            pvv[mt * 4 + rg] = v;
            tmax = fmaxf(tmax, v);
          }
        } else {
          #pragma unroll
          for (int rg = 0; rg < 4; ++rg) pvv[mt * 4 + rg] = -3.0e38f;
        }
      }

      // ---- online softmax per column (q = c) ----
      tmax = fmaxf(tmax, __shfl_xor(tmax, 16));
      tmax = fmaxf(tmax, __shfl_xor(tmax, 32));
      const float m_new = fmaxf(m_run, tmax);
      const float alpha = __expf(m_run - m_new);
      float tsum = 0.f;
      #pragma unroll
      for (int i = 0; i < 16; ++i) {
        pvv[i] = __expf(pvv[i] - m_new);
        tsum += pvv[i];
      }
      tsum += __shfl_xor(tsum, 16);
      tsum += __shfl_xor(tsum, 32);
      l_run = l_run * alpha + tsum;
      m_run = m_new;

      // ---- P^T -> B-operand frags per 32-key chunk ----
      bf16x8 pb[2];
      const int sq2 = (Q & 1) << 1;
      #pragma unroll
      for (int kc = 0; kc < 2; ++kc) {
        unsigned int pk0[2], pk1[2];
        pk0[0] = pack2bf(pvv[kc * 8 + 0], pvv[kc * 8 + 1]);
        pk0[1] = pack2bf(pvv[kc * 8 + 2], pvv[kc * 8 + 3]);
        pk1[0] = pack2bf(pvv[kc * 8 + 4], pvv[kc * 8 + 5]);
        pk1[1] = pack2bf(pvv[kc * 8 + 6], pvv[kc * 8 + 7]);
        int dw[4];
        #pragma unroll
        for (int d = 0; d < 4; ++d) {
          const int src = ((sq2 + (d >> 1)) << 4) + c;
          const int v0 = __shfl((int)pk0[d & 1], src);
          const int v1 = __shfl((int)pk1[d & 1], src);
          dw[d] = (Q >= 2) ? v1 : v0;
        }
        int4 bi = make_int4(dw[0], dw[1], dw[2], dw[3]);
        pb[kc] = *(bf16x8*)&bi;
      }

      // ---- O^T += V^T . P^T  (2 key-chunks x 4 d-chunks) ----
      #pragma unroll
      for (int ch = 0; ch < 4; ++ch)
        #pragma unroll
        for (int t2 = 0; t2 < 4; ++t2) o[ch][t2] *= alpha;
      #pragma unroll
      for (int kc = 0; kc < 2; ++kc) {
        if (k0 + kc * 32 <= mylastk) {
          #pragma unroll
          for (int ch = 0; ch < 4; ++ch) {
            bf16x8 af =
                *(const bf16x8*)&Vt[half][(ch * 16 + c) * 72 + kc * 32 + Q * 8];
            o[ch] = __builtin_amdgcn_mfma_f32_16x16x32_bf16(af, pb[kc], o[ch],
                                                            0, 0, 0);
          }
        }
      }
    }
  }

  // ---- merge the two key-half partials (LDS, intra-block) ----
  __syncthreads();                       // all K/V LDS reads done; reuse it
  float* obuf = (float*)&Ks[0][0];       // [4 waves][64 lanes][stride 17] f32
  float* mlb  = (float*)&Vt[0][0];       // [4 waves][32] f32 (m then l)
  if (half && nqw > 0) {
    float* ob = &obuf[(wq * 64 + lane) * 17];   // stride 17: conflict-free
    #pragma unroll
    for (int ch = 0; ch < 4; ++ch)
      #pragma unroll
      for (int t2 = 0; t2 < 4; ++t2) ob[ch * 4 + t2] = o[ch][t2];
    if (Q == 0) { mlb[wq * 32 + c] = m_run; mlb[wq * 32 + 16 + c] = l_run; }
  }
  __syncthreads();

  // ---- epilogue: O[q][d] = (wA*oA + wB*oB)[d][q] / L  (waves 0-3) ----
  if (!half && nqw > 0 && c < nqw) {
    const float mB = mlb[wq * 32 + c];
    const float lB = mlb[wq * 32 + 16 + c];
    const float M  = fmaxf(m_run, mB);
    const float wA = __expf(m_run - M);   // exp(-3e38 - M) == 0 handles empty
    const float wB = __expf(mB - M);      // halves / fully-masked partials
    const float invl = 1.f / (wA * l_run + wB * lB);
    const float* ob = &obuf[(wq * 64 + lane) * 17];
    const int tok = r + (q0 + qb + c) * p;
    unsigned int* dst =
        (unsigned int*)(ao + (size_t)(b * T_ + tok) * D_ + h * HD_);
    #pragma unroll
    for (int ch = 0; ch < 4; ++ch)
      #pragma unroll
      for (int rp = 0; rp < 2; ++rp) {
        const int dhalf = ch * 16 + Q * 4 + rp * 2;   // even
        const float v0 =
            (wA * o[ch][rp * 2]     + wB * ob[ch * 4 + rp * 2])     * invl;
        const float v1 =
            (wA * o[ch][rp * 2 + 1] + wB * ob[ch * 4 + rp * 2 + 1]) * invl;
        dst[dhalf >> 1] = pack2bf(v0, v1);
      }
  }
}

// ---------------------------------------------------------------------------
extern "C" void kernel_launch(void* const* d_in, const int* in_sizes, int n_in,
                              void* d_out, int out_size, void* d_ws, size_t ws_size,
                              hipStream_t stream) {
  const float* x      = (const float*)d_in[0];   // (B,T,D)
  const int*   period = (const int*)  d_in[1];   // (B,H)
  const float* w_qkv  = (const float*)d_in[2];   // (3D, D)
  const float* b_qkv  = (const float*)d_in[3];   // (3D,)
  const float* w_out  = (const float*)d_in[4];   // (D, D)
  const float* b_out  = (const float*)d_in[5];   // (D,)
  float* out = (float*)d_out;                    // (B,T,D)

  const int M = B_ * T_;                         // 4096

  // ws layout (MB): xb[0,4) wqb[4,5.5) wob[5.5,6) qkvb[6,18)
  char* ws = (char*)d_ws;
  unsigned short* xb   = (unsigned short*)(ws);
  unsigned short* wqb  = (unsigned short*)(ws + (size_t)M * D_ * 2);
  unsigned short* wob  = (unsigned short*)(ws + (size_t)M * D_ * 2
                                              + (size_t)QKVS * D_ * 2);
  unsigned short* qkvb = (unsigned short*)(ws + (size_t)M * D_ * 2
                                              + (size_t)QKVS * D_ * 2
                                              + (size_t)D_ * D_ * 2);
  unsigned short* aob  = xb;   // alias: x_bf16 dead after GEMM1

  // fused input casts
  {
    const int n4 = (M * D_ + QKVS * D_ + D_ * D_) / 4;
    cast_all<<<dim3((n4 + 255) / 256), dim3(256), 0, stream>>>(
        x, w_qkv, w_out, xb, wqb, wob);
  }

  // 1) QKV projection -> bf16 token-major qkvb (128x64 tile, BK=128, grid 768)
  gemm_nt_bk128<1><<<dim3(QKVS / 64, M / 128), dim3(256), 0, stream>>>(
      xb, wqb, b_qkv, qkvb, M, QKVS, D_);

  // 2) residue-class flash attention, split-K halves (512 threads) -> aob
  attn_flash4<<<dim3(16, 63), dim3(512), 0, stream>>>(qkvb, period, aob);

  // 3) output projection -> fp32 out (128x64 tile, BK=128, grid 256)
  gemm_nt_bk128<0><<<dim3(D_ / 64, M / 128), dim3(256), 0, stream>>>(
      aob, wob, b_out, out, M, D_, D_);
}